// Round 5
// baseline (99198.462 us; speedup 1.0000x reference)
//
#include <hip/hip_runtime.h>
#include <hip/hip_fp16.h>

#define LOG2E 1.44269504088896340736f
#define BB 256
#define TT 128
#define SS 128
#define UU 256

// ---------------- parameter precompute ----------------
// sigmoid(sigma*(v-mu)) = 1/(1+2^(a*v+b)), a=-sigma*log2e, b=sigma*mu*log2e
// rab[i*UU+j]      : uint = half2(a,b)
// rw2[(i/2)*UU+j]  : uint = half2(wsig_i, wsig_{i+1}),  wsig = softplus(w)*erev
// num += wsig*s ; den += |wsig|*s
__global__ __launch_bounds__(256) void prep_kernel(
    const float* __restrict__ sensory_w, const float* __restrict__ sensory_mu,
    const float* __restrict__ sensory_sigma, const float* __restrict__ sensory_erev,
    const float* __restrict__ w, const float* __restrict__ mu,
    const float* __restrict__ sigma, const float* __restrict__ erev,
    const float* __restrict__ gleak, const float* __restrict__ vleak,
    const float* __restrict__ cm,
    unsigned int* __restrict__ rab, unsigned int* __restrict__ rw2,
    unsigned int* __restrict__ sab, unsigned int* __restrict__ sw2,
    float* __restrict__ cmt, float* __restrict__ gnum, float* __restrict__ cden)
{
    int e = blockIdx.x * 256 + threadIdx.x;
    int i = e >> 8;
    if (e < UU * UU) {
        float sg = sigma[e], m = mu[e];
        __half2 ab = __floats2half2_rn(-sg * LOG2E, sg * m * LOG2E);
        rab[e] = *(unsigned int*)&ab;
        if ((i & 1) == 0) {
            float w0 = log1pf(expf(w[e])) * erev[e];
            float w1 = log1pf(expf(w[e + UU])) * erev[e + UU];
            __half2 wp = __floats2half2_rn(w0, w1);
            rw2[(i >> 1) * UU + (e & (UU - 1))] = *(unsigned int*)&wp;
        }
    }
    if (e < SS * UU) {
        float sg = sensory_sigma[e], m = sensory_mu[e];
        __half2 ab = __floats2half2_rn(-sg * LOG2E, sg * m * LOG2E);
        sab[e] = *(unsigned int*)&ab;
        if ((i & 1) == 0) {
            float w0 = log1pf(expf(sensory_w[e])) * sensory_erev[e];
            float w1 = log1pf(expf(sensory_w[e + UU])) * sensory_erev[e + UU];
            __half2 wp = __floats2half2_rn(w0, w1);
            sw2[(i >> 1) * UU + (e & (UU - 1))] = *(unsigned int*)&wp;
        }
    }
    if (e < UU) {
        float gl = log1pf(expf(gleak[e]));
        float c = log1pf(expf(cm[e])) * 6.0f;   // ODE_UNFOLDS=6, ts=1
        cmt[e] = c;
        gnum[e] = gl * vleak[e];
        cden[e] = c + gl + 1e-8f;
    }
}

// f32 sigmoid with f16 params (folds to v_fma_mix_f32 + v_exp_f32 + v_rcp_f32)
__device__ __forceinline__ float sigz(unsigned int ab, float vk) {
    __half2 h = *(__half2*)&ab;
    float z = fmaf(__half2float(__low2half(h)), vk, __half2float(__high2half(h)));
    float e = __builtin_amdgcn_exp2f(z);
    return __builtin_amdgcn_rcpf(1.0f + e);
}
__device__ __forceinline__ void accum(unsigned int w2, float s0, float s1,
                                      float& num, float& den) {
    __half2 h = *(__half2*)&w2;
    float w0 = __half2float(__low2half(h));
    float w1 = __half2float(__high2half(h));
    num = fmaf(w0, s0, num); den = fmaf(fabsf(w0), s0, den);
    num = fmaf(w1, s1, num); den = fmaf(fabsf(w1), s1, den);
}

#define RL0(K) __int_as_float(__builtin_amdgcn_readlane(__float_as_int(v0), (K)))
#define RL1(K) __int_as_float(__builtin_amdgcn_readlane(__float_as_int(v1), (K)))

// ---------------- main kernel: 1 block = 1 batch element, 8 waves of 64 ----------------
// 512 threads => 2 waves/SIMD => 256-VGPR budget: params are TRULY register-resident.
// wave (qi=wv&1, qj=wv>>1): column j = 64*qj + l; rows i in [128qi, 128qi+128).
// Per lane: 128 ab uints + 64 w2 uints = 192 VGPRs.
// v lane-distributed twice per wave: lane l holds v0=v[128qi+l], v1=v[128qi+64+l].
// 1 barrier per unfold (double-buffered partials), redundant per-wave v-update.
__global__ __launch_bounds__(512, 2) void ltc_kernel(
    const float* __restrict__ x,
    const float* __restrict__ input_w, const float* __restrict__ input_b,
    const float* __restrict__ halt_w, const float* __restrict__ halt_b,
    const float* __restrict__ out_w, const float* __restrict__ out_b,
    const unsigned int* __restrict__ rab, const unsigned int* __restrict__ rw2,
    const unsigned int* __restrict__ sab, const unsigned int* __restrict__ sw2,
    const float* __restrict__ cmt_g, const float* __restrict__ gnum_g,
    const float* __restrict__ cden_g,
    float* __restrict__ readout, float* __restrict__ h_state, float* __restrict__ ponder_out)
{
    const int b = blockIdx.x, tid = threadIdx.x;
    const int wv = tid >> 6, l = tid & 63;
    const int qi = wv & 1, qj = wv >> 1;
    const int j = (qj << 6) + l;
    const int u0 = (qi << 7) + l;        // unit for v0
    const int u1 = u0 + 64;              // unit for v1

    __shared__ float2 part[2][2][UU];    // 8 KB (num,den), double-buffered
    __shared__ float xin_sh[SS];
    __shared__ float red[2];

    // ---- register-resident recurrent params: 192 VGPRs ----
    unsigned int rg_ab[128];
    unsigned int rg_w2[64];
#pragma unroll
    for (int k = 0; k < 128; ++k) rg_ab[k] = rab[(((qi << 7) + k) << 8) + j];
#pragma unroll
    for (int m = 0; m < 64; ++m) rg_w2[m] = rw2[(((qi << 6) + m) << 8) + j];

    const float cmt0 = cmt_g[u0], gnu0 = gnum_g[u0], cdu0 = cden_g[u0];
    const float cmt1 = cmt_g[u1], gnu1 = gnum_g[u1], cdu1 = cden_g[u1];
    const float hw0 = halt_w[u0], hw1 = halt_w[u1];
    const float ow0 = out_w[u0], ob0 = out_b[u0];
    const float ow1 = out_w[u1], ob1 = out_b[u1];
    const float hb = halt_b[0];
    float iw = 0.f, ibv = 0.f;
    if (tid < SS) { iw = input_w[tid]; ibv = input_b[tid]; }

    float v0 = 0.0f, v1 = 0.0f;
    float pond = 0.0f;
    __syncthreads();

    for (int t = 0; t < TT; ++t) {
        // ---- input mapping ----
        if (tid < SS) xin_sh[tid] = fmaf(x[((size_t)b * TT + t) * SS + tid], iw, ibv);
        __syncthreads();

        // ---- sensory partials: rows [64qi, 64qi+64), streamed from L2 ----
        {
            float num = 0.f, den = 0.f;
#pragma unroll 4
            for (int m = 0; m < 32; ++m) {
                int row = (qi << 6) + 2 * m;
                unsigned int ab0 = sab[(row << 8) + j];
                unsigned int ab1 = sab[((row + 1) << 8) + j];
                unsigned int wp  = sw2[(((qi << 5) + m) << 8) + j];
                float s0 = sigz(ab0, xin_sh[row]);
                float s1 = sigz(ab1, xin_sh[row + 1]);
                accum(wp, s0, s1, num, den);
            }
            part[0][qi][j] = make_float2(num, den);
        }
        __syncthreads();
        float basen0, based0, basen1, based1;
        {
            float2 a0 = part[0][0][u0], a1 = part[0][1][u0];
            basen0 = a0.x + a1.x + gnu0;
            based0 = a0.y + a1.y + cdu0;
            float2 b0 = part[0][0][u1], b1 = part[0][1][u1];
            basen1 = b0.x + b1.x + gnu1;
            based1 = b0.y + b1.y + cdu1;
        }

        int pb = 1;
        float accA0 = 0.0f, accA1 = 0.0f, halt_sum = 0.0f, rem = 0.0f;
        int nupd = 0;

        // ---- ACT loop (uniform early exit) ----
#pragma unroll 1
        for (int n = 0; n < 10; ++n) {
#pragma unroll 1
            for (int uu = 0; uu < 6; ++uu) {
                float num = 0.f, den = 0.f;
#pragma unroll
                for (int m = 0; m < 32; ++m) {        // rows 128qi + [0,64): v0 lanes
                    float a0 = RL0(2 * m), a1 = RL0(2 * m + 1);
                    float s0 = sigz(rg_ab[2 * m], a0);
                    float s1 = sigz(rg_ab[2 * m + 1], a1);
                    accum(rg_w2[m], s0, s1, num, den);
                }
#pragma unroll
                for (int m = 32; m < 64; ++m) {       // rows 128qi + [64,128): v1 lanes
                    float a0 = RL1(2 * m - 64), a1 = RL1(2 * m - 63);
                    float s0 = sigz(rg_ab[2 * m], a0);
                    float s1 = sigz(rg_ab[2 * m + 1], a1);
                    accum(rg_w2[m], s0, s1, num, den);
                }
                part[pb][qi][j] = make_float2(num, den);
                __syncthreads();
                // redundant per-wave v-update for own units
                float2 p00 = part[pb][0][u0], p10 = part[pb][1][u0];
                float tn0 = p00.x + p10.x + basen0;
                float td0 = p00.y + p10.y + based0;
                v0 = fmaf(cmt0, v0, tn0) * __builtin_amdgcn_rcpf(td0);
                float2 p01 = part[pb][0][u1], p11 = part[pb][1][u1];
                float tn1 = p01.x + p11.x + basen1;
                float td1 = p01.y + p11.y + based1;
                v1 = fmaf(cmt1, v1, tn1) * __builtin_amdgcn_rcpf(td1);
                pb ^= 1;
            }

            // halting p = sigmoid(v . halt_w + hb); qj==0 waves (wv 0,1) hold all units
            if (qj == 0) {
                float hp = v0 * hw0 + v1 * hw1;
                hp += __shfl_down(hp, 32, 64);
                hp += __shfl_down(hp, 16, 64);
                hp += __shfl_down(hp, 8, 64);
                hp += __shfl_down(hp, 4, 64);
                hp += __shfl_down(hp, 2, 64);
                hp += __shfl_down(hp, 1, 64);
                if (l == 0) red[qi] = hp;
            }
            __syncthreads();
            float dot = red[0] + red[1] + hb;
            float pr = __builtin_amdgcn_rcpf(1.0f + __builtin_amdgcn_exp2f(-dot * LOG2E));
            float new_sum = halt_sum + pr;
            bool halting = (n == 9) || (new_sum >= 0.99f);
            float r = 1.0f - halt_sum;
            float wgt = halting ? r : pr;
            accA0 = fmaf(wgt, v0, accA0);
            accA1 = fmaf(wgt, v1, accA1);
            if (halting) rem += r;
            halt_sum = new_sum;
            ++nupd;
            if (halting) break;
        }

        // ---- t epilogue: new_state = accA ----
        if (qj == 0) {
            size_t off = ((size_t)b * TT + t) * UU;
            readout[off + u0] = fmaf(accA0, ow0, ob0);
            readout[off + u1] = fmaf(accA1, ow1, ob1);
        }
        v0 = accA0;
        v1 = accA1;
        pond += (float)nupd + rem;
    }

    if (qj == 0) {
        h_state[(size_t)b * UU + u0] = v0;
        h_state[(size_t)b * UU + u1] = v1;
    }
    if (tid == 0) atomicAdd(ponder_out, pond * (1.0f / BB));
}

// ---------------- launch ----------------
extern "C" void kernel_launch(void* const* d_in, const int* in_sizes, int n_in,
                              void* d_out, int out_size, void* d_ws, size_t ws_size,
                              hipStream_t stream)
{
    const float* x             = (const float*)d_in[0];
    const float* input_w       = (const float*)d_in[1];
    const float* input_b       = (const float*)d_in[2];
    const float* sensory_w     = (const float*)d_in[3];
    const float* sensory_mu    = (const float*)d_in[4];
    const float* sensory_sigma = (const float*)d_in[5];
    const float* sensory_erev  = (const float*)d_in[6];
    const float* w             = (const float*)d_in[7];
    const float* mu            = (const float*)d_in[8];
    const float* sigma         = (const float*)d_in[9];
    const float* erev          = (const float*)d_in[10];
    const float* gleak         = (const float*)d_in[11];
    const float* vleak         = (const float*)d_in[12];
    const float* cm            = (const float*)d_in[13];
    const float* output_w      = (const float*)d_in[14];
    const float* output_b      = (const float*)d_in[15];
    const float* halt_w        = (const float*)d_in[16];
    const float* halt_b        = (const float*)d_in[17];

    float* readout = (float*)d_out;
    float* h_state = readout + (size_t)BB * TT * UU;
    float* ponder  = h_state + (size_t)BB * UU;

    char* wsb = (char*)d_ws;
    unsigned int* rab = (unsigned int*)wsb;  wsb += (size_t)UU * UU * 4;
    unsigned int* rw2 = (unsigned int*)wsb;  wsb += (size_t)(UU / 2) * UU * 4;
    unsigned int* sab = (unsigned int*)wsb;  wsb += (size_t)SS * UU * 4;
    unsigned int* sw2 = (unsigned int*)wsb;  wsb += (size_t)(SS / 2) * UU * 4;
    float* cmt  = (float*)wsb;  wsb += (size_t)UU * 4;
    float* gnum = (float*)wsb;  wsb += (size_t)UU * 4;
    float* cden = (float*)wsb;  wsb += (size_t)UU * 4;

    hipMemsetAsync(ponder, 0, sizeof(float), stream);
    prep_kernel<<<(UU * UU) / 256, 256, 0, stream>>>(
        sensory_w, sensory_mu, sensory_sigma, sensory_erev,
        w, mu, sigma, erev, gleak, vleak, cm,
        rab, rw2, sab, sw2, cmt, gnum, cden);
    ltc_kernel<<<BB, 512, 0, stream>>>(
        x, input_w, input_b, halt_w, halt_b, output_w, output_b,
        rab, rw2, sab, sw2, cmt, gnum, cden,
        readout, h_state, ponder);
}

// Round 6
// 69277.594 us; speedup vs baseline: 1.4319x; 1.4319x over previous
//
#include <hip/hip_runtime.h>
#include <hip/hip_fp16.h>

#define LOG2E 1.44269504088896340736f
#define BB 256
#define TT 128
#define SS 128
#define UU 256

typedef unsigned int u32x16 __attribute__((ext_vector_type(16)));

// ---------------- parameter precompute ----------------
// sigmoid(sigma*(v-mu)) = 1/(1+2^(a*v+b)), a=-sigma*log2e, b=sigma*mu*log2e
// rab[i*UU+j]      : uint = half2(a,b)
// rw2[(i/2)*UU+j]  : uint = half2(wsig_i, wsig_{i+1}),  wsig = softplus(w)*erev
// num += wsig*s ; den += |wsig|*s
__global__ __launch_bounds__(256) void prep_kernel(
    const float* __restrict__ sensory_w, const float* __restrict__ sensory_mu,
    const float* __restrict__ sensory_sigma, const float* __restrict__ sensory_erev,
    const float* __restrict__ w, const float* __restrict__ mu,
    const float* __restrict__ sigma, const float* __restrict__ erev,
    const float* __restrict__ gleak, const float* __restrict__ vleak,
    const float* __restrict__ cm,
    unsigned int* __restrict__ rab, unsigned int* __restrict__ rw2,
    unsigned int* __restrict__ sab, unsigned int* __restrict__ sw2,
    float* __restrict__ cmt, float* __restrict__ gnum, float* __restrict__ cden)
{
    int e = blockIdx.x * 256 + threadIdx.x;
    int i = e >> 8;
    if (e < UU * UU) {
        float sg = sigma[e], m = mu[e];
        __half2 ab = __floats2half2_rn(-sg * LOG2E, sg * m * LOG2E);
        rab[e] = *(unsigned int*)&ab;
        if ((i & 1) == 0) {
            float w0 = log1pf(expf(w[e])) * erev[e];
            float w1 = log1pf(expf(w[e + UU])) * erev[e + UU];
            __half2 wp = __floats2half2_rn(w0, w1);
            rw2[(i >> 1) * UU + (e & (UU - 1))] = *(unsigned int*)&wp;
        }
    }
    if (e < SS * UU) {
        float sg = sensory_sigma[e], m = sensory_mu[e];
        __half2 ab = __floats2half2_rn(-sg * LOG2E, sg * m * LOG2E);
        sab[e] = *(unsigned int*)&ab;
        if ((i & 1) == 0) {
            float w0 = log1pf(expf(sensory_w[e])) * sensory_erev[e];
            float w1 = log1pf(expf(sensory_w[e + UU])) * sensory_erev[e + UU];
            __half2 wp = __floats2half2_rn(w0, w1);
            sw2[(i >> 1) * UU + (e & (UU - 1))] = *(unsigned int*)&wp;
        }
    }
    if (e < UU) {
        float gl = log1pf(expf(gleak[e]));
        float c = log1pf(expf(cm[e])) * 6.0f;   // ODE_UNFOLDS=6, ts=1
        cmt[e] = c;
        gnum[e] = gl * vleak[e];
        cden[e] = c + gl + 1e-8f;
    }
}

// f32 sigmoid with f16 params (folds to v_fma_mix_f32 + v_exp_f32 + v_rcp_f32)
__device__ __forceinline__ float sigz(unsigned int ab, float vk) {
    __half2 h = *(__half2*)&ab;
    float z = fmaf(__half2float(__low2half(h)), vk, __half2float(__high2half(h)));
    float e = __builtin_amdgcn_exp2f(z);
    return __builtin_amdgcn_rcpf(1.0f + e);
}
__device__ __forceinline__ void accum(unsigned int w2, float s0, float s1,
                                      float& num, float& den) {
    __half2 h = *(__half2*)&w2;
    float w0 = __half2float(__low2half(h));
    float w1 = __half2float(__high2half(h));
    num = fmaf(w0, s0, num); den = fmaf(fabsf(w0), s0, den);
    num = fmaf(w1, s1, num); den = fmaf(fabsf(w1), s1, den);
}

#define RLN(VV, K) __int_as_float(__builtin_amdgcn_readlane(__float_as_int(VV), (K)))

// process 16 rows: ab vector ABV (elements 0..15), w vector WV elements WOFF..WOFF+7,
// v-broadcast from VV lanes KOFF..KOFF+15
#define CH16(ABV, WV, WOFF, VV, KOFF) do {                                  \
    _Pragma("unroll")                                                       \
    for (int m_ = 0; m_ < 8; ++m_) {                                        \
        float a0_ = RLN(VV, (KOFF) + 2 * m_);                               \
        float a1_ = RLN(VV, (KOFF) + 2 * m_ + 1);                           \
        float s0_ = sigz((ABV)[2 * m_], a0_);                               \
        float s1_ = sigz((ABV)[2 * m_ + 1], a1_);                           \
        accum((WV)[(WOFF) + m_], s0_, s1_, num, den);                       \
    }                                                                       \
} while (0)

#define LOAD16_AB(V, BASE) do {                                             \
    _Pragma("unroll")                                                       \
    for (int k_ = 0; k_ < 16; ++k_)                                         \
        (V)[k_] = rab[(((BASE) + k_) << 8) + j];                            \
} while (0)
#define LOAD16_W(V, BASE) do {                                              \
    _Pragma("unroll")                                                       \
    for (int k_ = 0; k_ < 16; ++k_)                                         \
        (V)[k_] = rw2[(((BASE) + k_) << 8) + j];                            \
} while (0)

// ---------------- main kernel: 1 block = 1 batch element, 8 waves of 64 ----------------
// amdgpu_waves_per_eu(2,2): allocator pinned to 2 waves/EU => 256 VGPR budget.
// Params live in ext_vector SSA values (never allocas): 8x u32x16 ab + 4x u32x16 w2
// = 192 VGPRs/lane. wave (qi=wv&1, qj=wv>>1): column j = 64*qj + l; rows [128qi,128qi+128).
// v lane-distributed: lane l holds v0=v[128qi+l], v1=v[128qi+64+l].
// 1 barrier per unfold (double-buffered partials), redundant per-wave v-update.
__global__ __launch_bounds__(512)
__attribute__((amdgpu_waves_per_eu(2, 2)))
void ltc_kernel(
    const float* __restrict__ x,
    const float* __restrict__ input_w, const float* __restrict__ input_b,
    const float* __restrict__ halt_w, const float* __restrict__ halt_b,
    const float* __restrict__ out_w, const float* __restrict__ out_b,
    const unsigned int* __restrict__ rab, const unsigned int* __restrict__ rw2,
    const unsigned int* __restrict__ sab, const unsigned int* __restrict__ sw2,
    const float* __restrict__ cmt_g, const float* __restrict__ gnum_g,
    const float* __restrict__ cden_g,
    float* __restrict__ readout, float* __restrict__ h_state, float* __restrict__ ponder_out)
{
    const int b = blockIdx.x, tid = threadIdx.x;
    const int wv = tid >> 6, l = tid & 63;
    const int qi = wv & 1, qj = wv >> 1;
    const int j = (qj << 6) + l;
    const int u0 = (qi << 7) + l;        // unit for v0
    const int u1 = u0 + 64;              // unit for v1

    __shared__ float2 part[2][2][UU];    // 8 KB (num,den), double-buffered
    __shared__ float xin_sh[SS];
    __shared__ float red[2];

    // ---- register-resident recurrent params as SSA vectors: 192 VGPRs ----
    const int rbase = qi << 7;           // first row of this wave's slice
    const int pbase = qi << 6;           // first row-pair
    u32x16 ab0, ab1, ab2, ab3, ab4, ab5, ab6, ab7;
    u32x16 wa, wb, wc, wd;
    LOAD16_AB(ab0, rbase + 0);   LOAD16_AB(ab1, rbase + 16);
    LOAD16_AB(ab2, rbase + 32);  LOAD16_AB(ab3, rbase + 48);
    LOAD16_AB(ab4, rbase + 64);  LOAD16_AB(ab5, rbase + 80);
    LOAD16_AB(ab6, rbase + 96);  LOAD16_AB(ab7, rbase + 112);
    LOAD16_W(wa, pbase + 0);     LOAD16_W(wb, pbase + 16);
    LOAD16_W(wc, pbase + 32);    LOAD16_W(wd, pbase + 48);

    const float cmt0 = cmt_g[u0], gnu0 = gnum_g[u0], cdu0 = cden_g[u0];
    const float cmt1 = cmt_g[u1], gnu1 = gnum_g[u1], cdu1 = cden_g[u1];
    const float hw0 = halt_w[u0], hw1 = halt_w[u1];
    const float ow0 = out_w[u0], ob0 = out_b[u0];
    const float ow1 = out_w[u1], ob1 = out_b[u1];
    const float hb = halt_b[0];
    float iw = 0.f, ibv = 0.f;
    if (tid < SS) { iw = input_w[tid]; ibv = input_b[tid]; }

    float v0 = 0.0f, v1 = 0.0f;
    float pond = 0.0f;
    __syncthreads();

    for (int t = 0; t < TT; ++t) {
        // ---- input mapping ----
        if (tid < SS) xin_sh[tid] = fmaf(x[((size_t)b * TT + t) * SS + tid], iw, ibv);
        __syncthreads();

        // ---- sensory partials: rows [64qi, 64qi+64), streamed from L2 ----
        {
            float num = 0.f, den = 0.f;
#pragma unroll 4
            for (int m = 0; m < 32; ++m) {
                int row = (qi << 6) + 2 * m;
                unsigned int sab0 = sab[(row << 8) + j];
                unsigned int sab1 = sab[((row + 1) << 8) + j];
                unsigned int swp  = sw2[(((qi << 5) + m) << 8) + j];
                float s0 = sigz(sab0, xin_sh[row]);
                float s1 = sigz(sab1, xin_sh[row + 1]);
                accum(swp, s0, s1, num, den);
            }
            part[0][qi][j] = make_float2(num, den);
        }
        __syncthreads();
        float basen0, based0, basen1, based1;
        {
            float2 a0 = part[0][0][u0], a1 = part[0][1][u0];
            basen0 = a0.x + a1.x + gnu0;
            based0 = a0.y + a1.y + cdu0;
            float2 b0 = part[0][0][u1], b1 = part[0][1][u1];
            basen1 = b0.x + b1.x + gnu1;
            based1 = b0.y + b1.y + cdu1;
        }

        int pb = 1;
        float accA0 = 0.0f, accA1 = 0.0f, halt_sum = 0.0f, rem = 0.0f;
        int nupd = 0;

        // ---- ACT loop (uniform early exit) ----
#pragma unroll 1
        for (int n = 0; n < 10; ++n) {
#pragma unroll 1
            for (int uu = 0; uu < 6; ++uu) {
                float num = 0.f, den = 0.f;
                CH16(ab0, wa, 0, v0, 0);
                CH16(ab1, wa, 8, v0, 16);
                CH16(ab2, wb, 0, v0, 32);
                CH16(ab3, wb, 8, v0, 48);
                CH16(ab4, wc, 0, v1, 0);
                CH16(ab5, wc, 8, v1, 16);
                CH16(ab6, wd, 0, v1, 32);
                CH16(ab7, wd, 8, v1, 48);
                part[pb][qi][j] = make_float2(num, den);
                __syncthreads();
                // redundant per-wave v-update for own units
                float2 p00 = part[pb][0][u0], p10 = part[pb][1][u0];
                float tn0 = p00.x + p10.x + basen0;
                float td0 = p00.y + p10.y + based0;
                v0 = fmaf(cmt0, v0, tn0) * __builtin_amdgcn_rcpf(td0);
                float2 p01 = part[pb][0][u1], p11 = part[pb][1][u1];
                float tn1 = p01.x + p11.x + basen1;
                float td1 = p01.y + p11.y + based1;
                v1 = fmaf(cmt1, v1, tn1) * __builtin_amdgcn_rcpf(td1);
                pb ^= 1;
            }

            // halting p = sigmoid(v . halt_w + hb); qj==0 waves (wv 0,1) hold all units
            if (qj == 0) {
                float hp = v0 * hw0 + v1 * hw1;
                hp += __shfl_down(hp, 32, 64);
                hp += __shfl_down(hp, 16, 64);
                hp += __shfl_down(hp, 8, 64);
                hp += __shfl_down(hp, 4, 64);
                hp += __shfl_down(hp, 2, 64);
                hp += __shfl_down(hp, 1, 64);
                if (l == 0) red[qi] = hp;
            }
            __syncthreads();
            float dot = red[0] + red[1] + hb;
            float pr = __builtin_amdgcn_rcpf(1.0f + __builtin_amdgcn_exp2f(-dot * LOG2E));
            float new_sum = halt_sum + pr;
            bool halting = (n == 9) || (new_sum >= 0.99f);
            float r = 1.0f - halt_sum;
            float wgt = halting ? r : pr;
            accA0 = fmaf(wgt, v0, accA0);
            accA1 = fmaf(wgt, v1, accA1);
            if (halting) rem += r;
            halt_sum = new_sum;
            ++nupd;
            if (halting) break;
        }

        // ---- t epilogue: new_state = accA ----
        if (qj == 0) {
            size_t off = ((size_t)b * TT + t) * UU;
            readout[off + u0] = fmaf(accA0, ow0, ob0);
            readout[off + u1] = fmaf(accA1, ow1, ob1);
        }
        v0 = accA0;
        v1 = accA1;
        pond += (float)nupd + rem;
    }

    if (qj == 0) {
        h_state[(size_t)b * UU + u0] = v0;
        h_state[(size_t)b * UU + u1] = v1;
    }
    if (tid == 0) atomicAdd(ponder_out, pond * (1.0f / BB));
}

// ---------------- launch ----------------
extern "C" void kernel_launch(void* const* d_in, const int* in_sizes, int n_in,
                              void* d_out, int out_size, void* d_ws, size_t ws_size,
                              hipStream_t stream)
{
    const float* x             = (const float*)d_in[0];
    const float* input_w       = (const float*)d_in[1];
    const float* input_b       = (const float*)d_in[2];
    const float* sensory_w     = (const float*)d_in[3];
    const float* sensory_mu    = (const float*)d_in[4];
    const float* sensory_sigma = (const float*)d_in[5];
    const float* sensory_erev  = (const float*)d_in[6];
    const float* w             = (const float*)d_in[7];
    const float* mu            = (const float*)d_in[8];
    const float* sigma         = (const float*)d_in[9];
    const float* erev          = (const float*)d_in[10];
    const float* gleak         = (const float*)d_in[11];
    const float* vleak         = (const float*)d_in[12];
    const float* cm            = (const float*)d_in[13];
    const float* output_w      = (const float*)d_in[14];
    const float* output_b      = (const float*)d_in[15];
    const float* halt_w        = (const float*)d_in[16];
    const float* halt_b       = (const float*)d_in[17];

    float* readout = (float*)d_out;
    float* h_state = readout + (size_t)BB * TT * UU;
    float* ponder  = h_state + (size_t)BB * UU;

    char* wsb = (char*)d_ws;
    unsigned int* rab = (unsigned int*)wsb;  wsb += (size_t)UU * UU * 4;
    unsigned int* rw2 = (unsigned int*)wsb;  wsb += (size_t)(UU / 2) * UU * 4;
    unsigned int* sab = (unsigned int*)wsb;  wsb += (size_t)SS * UU * 4;
    unsigned int* sw2 = (unsigned int*)wsb;  wsb += (size_t)(SS / 2) * UU * 4;
    float* cmt  = (float*)wsb;  wsb += (size_t)UU * 4;
    float* gnum = (float*)wsb;  wsb += (size_t)UU * 4;
    float* cden = (float*)wsb;  wsb += (size_t)UU * 4;

    hipMemsetAsync(ponder, 0, sizeof(float), stream);
    prep_kernel<<<(UU * UU) / 256, 256, 0, stream>>>(
        sensory_w, sensory_mu, sensory_sigma, sensory_erev,
        w, mu, sigma, erev, gleak, vleak, cm,
        rab, rw2, sab, sw2, cmt, gnum, cden);
    ltc_kernel<<<BB, 512, 0, stream>>>(
        x, input_w, input_b, halt_w, halt_b, output_w, output_b,
        rab, rw2, sab, sw2, cmt, gnum, cden,
        readout, h_state, ponder);
}

// Round 7
// 13113.690 us; speedup vs baseline: 7.5645x; 5.2828x over previous
//
#include <hip/hip_runtime.h>
#include <hip/hip_fp16.h>

#define LOG2E 1.44269504088896340736f
#define BB 256
#define TT 128
#define SS 128
#define UU 256

// ---------------- packing helpers ----------------
__device__ __forceinline__ __half2 u2h(unsigned u) {
    union { unsigned x; __half2 h; } c; c.x = u; return c.h;
}
__device__ __forceinline__ unsigned h2u(__half2 h) {
    union { __half2 h; unsigned x; } c; c.h = h; return c.x;
}

// ---------------- parameter precompute ----------------
// sigmoid(sigma*(v-mu)) = 1/(1+2^(a*v+b)), a=-sigma*log2e, b=sigma*mu*log2e
// Group = 4 consecutive rows at one column j:
//   abq[g*256+j] = uint4{ h2(a_r0,a_r1), h2(b_r0,b_r1), h2(a_r2,a_r3), h2(b_r2,b_r3) }
//   wd [g*256+j] = uint2{ h2(w_r0,w_r1), h2(w_r2,w_r3) },  w = softplus(w)*erev (signed)
// num += w*s ; den += |w|*s  (abs = free v_fma_mix modifier)
__global__ __launch_bounds__(256) void prep_kernel(
    const float* __restrict__ sensory_w, const float* __restrict__ sensory_mu,
    const float* __restrict__ sensory_sigma, const float* __restrict__ sensory_erev,
    const float* __restrict__ w, const float* __restrict__ mu,
    const float* __restrict__ sigma, const float* __restrict__ erev,
    const float* __restrict__ gleak, const float* __restrict__ vleak,
    const float* __restrict__ cm,
    uint4* __restrict__ gabq, uint2* __restrict__ gwd,
    uint4* __restrict__ sabq, uint2* __restrict__ swd,
    float* __restrict__ cmt, float* __restrict__ gnum, float* __restrict__ cden)
{
    int e = blockIdx.x * 256 + threadIdx.x;
    int g = e >> 8, j = e & 255;
    if (e < 64 * 256) {                       // recurrent: 64 groups of 4 rows
        float aa[4], bb[4], ww[4];
#pragma unroll
        for (int k = 0; k < 4; ++k) {
            int idx = ((g << 2) + k) * UU + j;
            float sg = sigma[idx], m = mu[idx];
            aa[k] = -sg * LOG2E;
            bb[k] = sg * m * LOG2E;
            ww[k] = log1pf(expf(w[idx])) * erev[idx];
        }
        uint4 o;
        o.x = h2u(__floats2half2_rn(aa[0], aa[1]));
        o.y = h2u(__floats2half2_rn(bb[0], bb[1]));
        o.z = h2u(__floats2half2_rn(aa[2], aa[3]));
        o.w = h2u(__floats2half2_rn(bb[2], bb[3]));
        gabq[e] = o;
        uint2 o2;
        o2.x = h2u(__floats2half2_rn(ww[0], ww[1]));
        o2.y = h2u(__floats2half2_rn(ww[2], ww[3]));
        gwd[e] = o2;
    }
    if (e < 32 * 256) {                       // sensory: 32 groups of 4 rows
        float aa[4], bb[4], ww[4];
#pragma unroll
        for (int k = 0; k < 4; ++k) {
            int idx = ((g << 2) + k) * UU + j;
            float sg = sensory_sigma[idx], m = sensory_mu[idx];
            aa[k] = -sg * LOG2E;
            bb[k] = sg * m * LOG2E;
            ww[k] = log1pf(expf(sensory_w[idx])) * sensory_erev[idx];
        }
        uint4 o;
        o.x = h2u(__floats2half2_rn(aa[0], aa[1]));
        o.y = h2u(__floats2half2_rn(bb[0], bb[1]));
        o.z = h2u(__floats2half2_rn(aa[2], aa[3]));
        o.w = h2u(__floats2half2_rn(bb[2], bb[3]));
        sabq[e] = o;
        uint2 o2;
        o2.x = h2u(__floats2half2_rn(ww[0], ww[1]));
        o2.y = h2u(__floats2half2_rn(ww[2], ww[3]));
        swd[e] = o2;
    }
    if (e < UU) {
        float gl = log1pf(expf(gleak[e]));
        float c = log1pf(expf(cm[e])) * 6.0f;   // ODE_UNFOLDS=6, ts=1
        cmt[e] = c;
        gnum[e] = gl * vleak[e];
        cden[e] = c + gl + 1e-8f;
    }
}

// process 4 rows: packed f16 z, f16 exp/rcp, f32 mix-accumulate
__device__ __forceinline__ void proc4(uint4 qab, uint2 qw, unsigned pv01, unsigned pv23,
                                      float& num, float& den)
{
    const __half one = __ushort_as_half((unsigned short)0x3C00);
    __half2 z0 = __hfma2(u2h(qab.x), u2h(pv01), u2h(qab.y));
    __half2 z1 = __hfma2(u2h(qab.z), u2h(pv23), u2h(qab.w));
    float s0 = __half2float(hrcp(__hadd(hexp2(__low2half(z0)), one)));
    float s1 = __half2float(hrcp(__hadd(hexp2(__high2half(z0)), one)));
    float s2 = __half2float(hrcp(__hadd(hexp2(__low2half(z1)), one)));
    float s3 = __half2float(hrcp(__hadd(hexp2(__high2half(z1)), one)));
    float w0 = __half2float(__low2half(u2h(qw.x)));
    float w1 = __half2float(__high2half(u2h(qw.x)));
    float w2 = __half2float(__low2half(u2h(qw.y)));
    float w3 = __half2float(__high2half(u2h(qw.y)));
    num = fmaf(w0, s0, num); den = fmaf(fabsf(w0), s0, den);
    num = fmaf(w1, s1, num); den = fmaf(fabsf(w1), s1, den);
    num = fmaf(w2, s2, num); den = fmaf(fabsf(w2), s2, den);
    num = fmaf(w3, s3, num); den = fmaf(fabsf(w3), s3, den);
}

// pack two readlane'd f16 v values (SGPR path; s_pack_ll + SALU, off the VALU pipe)
#define PKRL(VH, A, B) ((unsigned)((__builtin_amdgcn_readlane((int)(VH), (A)) & 0xFFFF) | \
                                   (__builtin_amdgcn_readlane((int)(VH), (B)) << 16)))

// ---------------- main kernel: 1 block = 1 batch element, 16 waves ----------------
// wave (qi=wv&3, qj=wv>>2): columns j = 64qj+l, rows [64qi, 64qi+64) = 16 groups:
// groups 0..4 LDS-resident (80 rows total, 123 KB), groups 5..15 streamed from L2.
// v lane-distributed: lane l of qi-row waves holds v[64qi+l] (f32 + f16 bits vh).
// 1 barrier per unfold (double-buffered partials), redundant per-wave v-update.
__global__ __launch_bounds__(1024) void ltc_kernel(
    const float* __restrict__ x,
    const float* __restrict__ input_w, const float* __restrict__ input_b,
    const float* __restrict__ halt_w, const float* __restrict__ halt_b,
    const float* __restrict__ out_w, const float* __restrict__ out_b,
    const uint4* __restrict__ gabq, const uint2* __restrict__ gwd,
    const uint4* __restrict__ sabq, const uint2* __restrict__ swd,
    const float* __restrict__ cmt_g, const float* __restrict__ gnum_g,
    const float* __restrict__ cden_g,
    float* __restrict__ readout, float* __restrict__ h_state, float* __restrict__ ponder_out)
{
    const int b = blockIdx.x, tid = threadIdx.x;
    const int wv = tid >> 6, l = tid & 63;
    const int qi = wv & 3, qj = wv >> 2;
    const int j = (qj << 6) + l;
    const int u = (qi << 6) + l;

    __shared__ uint4 labq[5120];          // 80 KB: ab for groups (qi,c<5)
    __shared__ uint2 lwd[5120];           // 40 KB: w  for groups (qi,c<5)
    __shared__ float2 part[2][4][UU];     // 16 KB (num,den), double-buffered
    __shared__ unsigned xin2[64];         // packed half2 xin pairs
    __shared__ float red[4];

    // ---- stage LDS param groups (5 per qi): flat e = qi*1280 + c*256 + j ----
#pragma unroll
    for (int m = 0; m < 5; ++m) {
        int e = m * 1024 + tid;
        int qis = e / 1280;
        int rem = e - qis * 1280;         // c*256 + j, c<5
        labq[e] = gabq[qis * 4096 + rem];
        lwd[e]  = gwd[qis * 4096 + rem];
    }

    const float cmtu = cmt_g[u], gnu = gnum_g[u], cdu = cden_g[u];
    const float hwu = halt_w[u], owu = out_w[u], obu = out_b[u];
    const float hb = halt_b[0];
    float2 iw2 = {0.f, 0.f}, ib2 = {0.f, 0.f};
    if (tid < 64) {
        iw2 = ((const float2*)input_w)[tid];
        ib2 = ((const float2*)input_b)[tid];
    }

    float v = 0.0f;
    int vh = 0;               // f16 bits of v, low 16
    float pond = 0.0f;
    __syncthreads();

    for (int t = 0; t < TT; ++t) {
        // ---- input mapping: packed half2 pairs ----
        if (tid < 64) {
            float2 xv = ((const float2*)(x + ((size_t)b * TT + t) * SS))[tid];
            xin2[tid] = h2u(__floats2half2_rn(fmaf(xv.x, iw2.x, ib2.x),
                                              fmaf(xv.y, iw2.y, ib2.y)));
        }
        __syncthreads();

        // ---- sensory partials: 8 groups (rows [32qi,32qi+32)), L2-streamed ----
        {
            float num = 0.f, den = 0.f;
            const uint4* pA = sabq + ((qi << 3) << 8) + j;
            const uint2* pW = swd + ((qi << 3) << 8) + j;
            uint4 qa = pA[0]; uint2 qw = pW[0];
#pragma unroll 1
            for (int c = 0; c < 8; ++c) {
                uint4 na = qa; uint2 nw = qw;
                if (c < 7) { na = pA[(c + 1) << 8]; nw = pW[(c + 1) << 8]; }
                uint2 xp = *(const uint2*)&xin2[((qi << 3) + c) << 1];
                proc4(qa, qw, xp.x, xp.y, num, den);
                qa = na; qw = nw;
            }
            part[0][qi][j] = make_float2(num, den);
        }
        __syncthreads();
        float basen, based;
        {
            float2 s0 = part[0][0][u], s1 = part[0][1][u];
            float2 s2 = part[0][2][u], s3 = part[0][3][u];
            basen = s0.x + s1.x + s2.x + s3.x + gnu;
            based = s0.y + s1.y + s2.y + s3.y + cdu;
        }

        int pb = 1;
        float accA = 0.0f, halt_sum = 0.0f, rem = 0.0f;
        int nupd = 0;

        // ---- ACT loop (uniform early exit) ----
#pragma unroll 1
        for (int n = 0; n < 10; ++n) {
#pragma unroll 1
            for (int uu = 0; uu < 6; ++uu) {
                float num = 0.f, den = 0.f;
                // 5 LDS groups (local rows 0..19)
#pragma unroll
                for (int c = 0; c < 5; ++c) {
                    uint4 qa = labq[((qi * 5 + c) << 8) + j];
                    uint2 qw = lwd[((qi * 5 + c) << 8) + j];
                    unsigned p01 = PKRL(vh, 4 * c, 4 * c + 1);
                    unsigned p23 = PKRL(vh, 4 * c + 2, 4 * c + 3);
                    proc4(qa, qw, p01, p23, num, den);
                }
                // 11 global groups (local rows 20..63), 1-ahead prefetch
                {
                    const uint4* pA = gabq + ((qi * 16 + 5) << 8) + j;
                    const uint2* pW = gwd + ((qi * 16 + 5) << 8) + j;
                    uint4 qa = pA[0]; uint2 qw = pW[0];
#pragma unroll 1
                    for (int c = 5; c < 16; ++c) {
                        uint4 na = qa; uint2 nw = qw;
                        if (c < 15) { na = pA[(c - 4) << 8]; nw = pW[(c - 4) << 8]; }
                        unsigned p01 = PKRL(vh, 4 * c, 4 * c + 1);
                        unsigned p23 = PKRL(vh, 4 * c + 2, 4 * c + 3);
                        proc4(qa, qw, p01, p23, num, den);
                        qa = na; qw = nw;
                    }
                }
                part[pb][qi][j] = make_float2(num, den);
                __syncthreads();
                // redundant per-wave v-update for own units
                float2 p0 = part[pb][0][u], p1 = part[pb][1][u];
                float2 p2 = part[pb][2][u], p3 = part[pb][3][u];
                float tn = p0.x + p1.x + p2.x + p3.x + basen;
                float td = p0.y + p1.y + p2.y + p3.y + based;
                v = fmaf(cmtu, v, tn) * __builtin_amdgcn_rcpf(td);
                vh = (int)__half_as_ushort(__float2half(v));
                pb ^= 1;
            }

            // halting p = sigmoid(v . halt_w + hb); qj==0 waves hold all 256 units
            if (qj == 0) {
                float hp = v * hwu;
                hp += __shfl_down(hp, 32, 64);
                hp += __shfl_down(hp, 16, 64);
                hp += __shfl_down(hp, 8, 64);
                hp += __shfl_down(hp, 4, 64);
                hp += __shfl_down(hp, 2, 64);
                hp += __shfl_down(hp, 1, 64);
                if (l == 0) red[qi] = hp;
            }
            __syncthreads();
            float dot = red[0] + red[1] + red[2] + red[3] + hb;
            float pr = __builtin_amdgcn_rcpf(1.0f + __builtin_amdgcn_exp2f(-dot * LOG2E));
            float new_sum = halt_sum + pr;
            bool halting = (n == 9) || (new_sum >= 0.99f);
            float r = 1.0f - halt_sum;
            float wgt = halting ? r : pr;
            accA = fmaf(wgt, v, accA);
            if (halting) rem += r;
            halt_sum = new_sum;
            ++nupd;
            if (halting) break;
        }

        // ---- t epilogue: new_state = accA ----
        if (qj == 0)
            readout[((size_t)b * TT + t) * UU + u] = fmaf(accA, owu, obu);
        v = accA;
        vh = (int)__half_as_ushort(__float2half(v));
        pond += (float)nupd + rem;
    }

    if (qj == 0) h_state[(size_t)b * UU + u] = v;
    if (tid == 0) atomicAdd(ponder_out, pond * (1.0f / BB));
}

// ---------------- launch ----------------
extern "C" void kernel_launch(void* const* d_in, const int* in_sizes, int n_in,
                              void* d_out, int out_size, void* d_ws, size_t ws_size,
                              hipStream_t stream)
{
    const float* x             = (const float*)d_in[0];
    const float* input_w       = (const float*)d_in[1];
    const float* input_b       = (const float*)d_in[2];
    const float* sensory_w     = (const float*)d_in[3];
    const float* sensory_mu    = (const float*)d_in[4];
    const float* sensory_sigma = (const float*)d_in[5];
    const float* sensory_erev  = (const float*)d_in[6];
    const float* w             = (const float*)d_in[7];
    const float* mu            = (const float*)d_in[8];
    const float* sigma         = (const float*)d_in[9];
    const float* erev          = (const float*)d_in[10];
    const float* gleak         = (const float*)d_in[11];
    const float* vleak         = (const float*)d_in[12];
    const float* cm            = (const float*)d_in[13];
    const float* output_w      = (const float*)d_in[14];
    const float* output_b      = (const float*)d_in[15];
    const float* halt_w        = (const float*)d_in[16];
    const float* halt_b        = (const float*)d_in[17];

    float* readout = (float*)d_out;
    float* h_state = readout + (size_t)BB * TT * UU;
    float* ponder  = h_state + (size_t)BB * UU;

    char* wsb = (char*)d_ws;
    uint4* gabq = (uint4*)wsb;  wsb += (size_t)64 * 256 * sizeof(uint4);
    uint2* gwd  = (uint2*)wsb;  wsb += (size_t)64 * 256 * sizeof(uint2);
    uint4* sabq = (uint4*)wsb;  wsb += (size_t)32 * 256 * sizeof(uint4);
    uint2* swd  = (uint2*)wsb;  wsb += (size_t)32 * 256 * sizeof(uint2);
    float* cmt  = (float*)wsb;  wsb += (size_t)UU * 4;
    float* gnum = (float*)wsb;  wsb += (size_t)UU * 4;
    float* cden = (float*)wsb;  wsb += (size_t)UU * 4;

    hipMemsetAsync(ponder, 0, sizeof(float), stream);
    prep_kernel<<<64, 256, 0, stream>>>(
        sensory_w, sensory_mu, sensory_sigma, sensory_erev,
        w, mu, sigma, erev, gleak, vleak, cm,
        gabq, gwd, sabq, swd, cmt, gnum, cden);
    ltc_kernel<<<BB, 1024, 0, stream>>>(
        x, input_w, input_b, halt_w, halt_b, output_w, output_b,
        gabq, gwd, sabq, swd, cmt, gnum, cden,
        readout, h_state, ponder);
}